// Round 14
// baseline (196.683 us; speedup 1.0000x reference)
//
#include <hip/hip_runtime.h>
#include <math.h>

#define B_  2
#define S_  2048
#define D_  1024
#define H_  16
#define HD_ 64
#define NT_ (S_/64)          // 32 key tiles
#define C2_ (0.125f * 1.44269504088896f)   // scale * log2(e)

typedef __attribute__((ext_vector_type(8))) _Float16 f16x8;
typedef __attribute__((ext_vector_type(2))) __fp16 h16x2;   // cvt_pkrtz return type
typedef __attribute__((ext_vector_type(4))) float f32x4;
typedef unsigned short u16;
typedef unsigned int   u32;

__device__ inline u16 f2h(float f) {             // RNE fp32->fp16 (HW cvt)
    union { _Float16 h; u16 u; } c; c.h = (_Float16)f;
    return c.u;
}
__device__ inline u32 pkrtz(float a, float b) {  // 1-inst pack: v_cvt_pkrtz_f16_f32
    union { h16x2 h; u32 u; } c;
    c.h = __builtin_amdgcn_cvt_pkrtz(a, b);
    return c.u;
}

// async global->LDS, 16 B per lane (dest = wave-uniform base + lane*16)
#define GLOAD_LDS16(g, l)                                                    \
    __builtin_amdgcn_global_load_lds(                                        \
        (const __attribute__((address_space(1))) void*)(g),                  \
        (__attribute__((address_space(3))) void*)(l), 16, 0, 0)

// ---------------------------------------------------------------------------
// Pre-cast all six tensors to fp16. z: 0=wq 1=wk 2=wv 3=q 4=k 5=v
// ---------------------------------------------------------------------------
__global__ __launch_bounds__(256)
void precast(const float* __restrict__ wq, const float* __restrict__ wk,
             const float* __restrict__ wv, const float* __restrict__ q,
             const float* __restrict__ k,  const float* __restrict__ v,
             u16* __restrict__ Wq, u16* __restrict__ Wk, u16* __restrict__ Wv,
             u16* __restrict__ Xq, u16* __restrict__ Xk, u16* __restrict__ Xv)
{
    const int z = blockIdx.y;
    const size_t n = (z >= 3) ? (size_t)B_ * S_ * D_ : (size_t)D_ * D_;
    const size_t i = ((size_t)blockIdx.x * 256 + threadIdx.x) * 4;
    if (i >= n) return;
    const float* src = (z == 0) ? wq : (z == 1) ? wk : (z == 2) ? wv
                     : (z == 3) ? q  : (z == 4) ? k  : v;
    u16* dst = (z == 0) ? Wq : (z == 1) ? Wk : (z == 2) ? Wv
             : (z == 3) ? Xq : (z == 4) ? Xk : Xv;
    float4 xv = *(const float4*)&src[i];
    *(ushort4*)&dst[i] = make_ushort4(f2h(xv.x), f2h(xv.y), f2h(xv.z), f2h(xv.w));
}

// ---------------------------------------------------------------------------
// Unified projection GEMM, fp16 — 128x128 tile, 4 waves (2M x 2N), BK=64,
// double-buffered counted-vmcnt pipeline (R12 best: 44.5 us). Unchanged.
// ---------------------------------------------------------------------------
__global__ __launch_bounds__(256, 2)
void proj_all(const u16* __restrict__ Xq, const u16* __restrict__ Xk,
              const u16* __restrict__ Xv, const u16* __restrict__ Wq,
              const u16* __restrict__ Wk, const u16* __restrict__ Wv,
              u16* __restrict__ QP, u16* __restrict__ KP, u16* __restrict__ VT)
{
    const int bid = (int)blockIdx.x;              // 0..767
    const int g   = (bid & 7) * 96 + (bid >> 3);  // bijective XCD chunking
    const int z   = g >> 8;                       // 0..2
    const int rem = g & 255;
    const int ny  = rem >> 3;                     // 0..31 (m panel)
    const int nx  = rem & 7;                      // 0..7  (n panel, fastest)

    const u16* X = (z == 0) ? Xq : (z == 1) ? Xk : Xv;
    const u16* W = (z == 0) ? Wq : (z == 1) ? Wk : Wv;

    __shared__ u16 Xs[2][128 * 64];   // linear [row][slot*8], swizzled content
    __shared__ u16 Ws[2][128 * 64];

    const int tid  = threadIdx.x;
    const int w    = tid >> 6;          // 0..3
    const int lane = tid & 63;
    const int quad = lane >> 4;
    const int lr   = lane & 15;
    const int wm   = w >> 1;            // 0..1 (M wave group)
    const int wn   = w & 1;             // 0..1 (N wave group)
    const int m0   = ny * 128;
    const int n0   = nx * 128;

    // --- staging geometry (per wave: 4 issues of 1 KB per matrix per buf) ---
    const int srow  = w * 32 + (lane >> 3);             // + c*8
    const int gslot = (lane & 7) ^ ((lane >> 3) & 7);   // inverse-swizzled src slot
    const size_t xbase = (size_t)(m0 + srow) * D_ + gslot * 8;
    const size_t wbase = (size_t)(n0 + srow) * D_ + gslot * 8;
    const int ldsoff = w * 2048 + lane * 8;             // + c*512 (elems)

    f32x4 acc[4][4];
    #pragma unroll
    for (int i = 0; i < 4; ++i)
        #pragma unroll
        for (int j = 0; j < 4; ++j) acc[i][j] = (f32x4){0.f, 0.f, 0.f, 0.f};

    // prologue: issue tile 0 into buffer 0 (8 loads outstanding)
    #pragma unroll
    for (int c = 0; c < 4; ++c) {
        GLOAD_LDS16(X + xbase + (size_t)c * 8 * D_, &Xs[0][ldsoff + c * 512]);
        GLOAD_LDS16(W + wbase + (size_t)c * 8 * D_, &Ws[0][ldsoff + c * 512]);
    }

    for (int t = 0; t < 16; ++t) {
        const int cur = t & 1;
        if (t < 15) {
            const size_t ko = (size_t)(t + 1) * 64;
            #pragma unroll
            for (int c = 0; c < 4; ++c) {
                GLOAD_LDS16(X + xbase + (size_t)c * 8 * D_ + ko,
                            &Xs[cur ^ 1][ldsoff + c * 512]);
                GLOAD_LDS16(W + wbase + (size_t)c * 8 * D_ + ko,
                            &Ws[cur ^ 1][ldsoff + c * 512]);
            }
            asm volatile("s_waitcnt vmcnt(8)" ::: "memory");
        } else {
            asm volatile("s_waitcnt vmcnt(0)" ::: "memory");
        }
        __builtin_amdgcn_s_barrier();   // (1) tile-t loads complete block-wide

        // ---- compute: 16 ds_read_b128 + 32 MFMA, compiler-interleaved ----
        f16x8 bf[4][2], af[4][2];
        #pragma unroll
        for (int fn = 0; fn < 4; ++fn) {
            const int row = wn * 64 + fn * 16 + lr;
            #pragma unroll
            for (int kk = 0; kk < 2; ++kk)
                bf[fn][kk] = *(const f16x8*)
                    &Ws[cur][row * 64 + (((kk * 4 + quad) ^ (lr & 7)) << 3)];
        }
        #pragma unroll
        for (int fm = 0; fm < 4; ++fm) {
            const int row = wm * 64 + fm * 16 + lr;
            #pragma unroll
            for (int kk = 0; kk < 2; ++kk)
                af[fm][kk] = *(const f16x8*)
                    &Xs[cur][row * 64 + (((kk * 4 + quad) ^ (lr & 7)) << 3)];
        }
        #pragma unroll
        for (int fm = 0; fm < 4; ++fm)
            #pragma unroll
            for (int fn = 0; fn < 4; ++fn)
                #pragma unroll
                for (int kk = 0; kk < 2; ++kk)
                    acc[fm][fn] = __builtin_amdgcn_mfma_f32_16x16x32_f16(
                        af[fm][kk], bf[fn][kk], acc[fm][fn], 0, 0, 0);
        __builtin_amdgcn_s_barrier();   // (2) reads of buf[cur] done before
                                        //     round t+1 re-stages into it
    }

    // ---- epilogue ----
    if (z < 2) {
        u16* P = (z == 0) ? QP : KP;
        const float sc = (z == 0) ? C2_ : 1.0f;   // fold softmax scale into Q
        #pragma unroll
        for (int fm = 0; fm < 4; ++fm)
            #pragma unroll
            for (int fn = 0; fn < 4; ++fn) {
                int n = n0 + wn * 64 + fn * 16 + lr;
                int h = n >> 6, hd = n & 63;
                #pragma unroll
                for (int r = 0; r < 4; ++r) {
                    int m = m0 + wm * 64 + fm * 16 + quad * 4 + r;
                    int b = m >> 11, s = m & (S_ - 1);
                    P[(((size_t)b * H_ + h) * S_ + s) * HD_ + hd] =
                        f2h(acc[fm][fn][r] * sc);
                }
            }
    } else {
        #pragma unroll
        for (int fm = 0; fm < 4; ++fm)
            #pragma unroll
            for (int fn = 0; fn < 4; ++fn) {
                int n  = n0 + wn * 64 + fn * 16 + lr;
                int h  = n >> 6, vd = n & 63;
                int m  = m0 + wm * 64 + fm * 16 + quad * 4;   // 4 consecutive s
                int b  = m >> 11, s = m & (S_ - 1);
                ushort4 pv = make_ushort4(f2h(acc[fm][fn][0]), f2h(acc[fm][fn][1]),
                                          f2h(acc[fm][fn][2]), f2h(acc[fm][fn][3]));
                *(ushort4*)&VT[(((size_t)b * H_ + h) * HD_ + vd) * S_ + s] = pv;
            }
    }
}

// ---------------------------------------------------------------------------
// V tile sums (fp16 VT, vectorized 16B loads) + suffix sums
// ---------------------------------------------------------------------------
__global__ __launch_bounds__(64)
void vtilesum_kernel(const u16* __restrict__ VT, float* __restrict__ TS)
{
    const int t = blockIdx.x, bh = blockIdx.y, vd = threadIdx.x;
    const u16* p = VT + ((size_t)bh * HD_ + vd) * S_ + t * 64;
    float acc = 0.f;
    #pragma unroll
    for (int c = 0; c < 8; ++c) {
        f16x8 vv = *(const f16x8*)&p[c * 8];
        #pragma unroll
        for (int j = 0; j < 8; ++j) acc += (float)vv[j];
    }
    TS[((size_t)bh * NT_ + t) * HD_ + vd] = acc;
}

__global__ __launch_bounds__(64)
void vsuffix_kernel(const float* __restrict__ TS, float* __restrict__ SUF)
{
    const int bh = blockIdx.x, c = threadIdx.x;
    float acc = 0.f;
    SUF[((size_t)bh * (NT_ + 1) + NT_) * HD_ + c] = 0.f;
    for (int t = NT_ - 1; t >= 0; --t) {
        acc += TS[((size_t)bh * NT_ + t) * HD_ + c];
        SUF[((size_t)bh * (NT_ + 1) + t) * HD_ + c] = acc;
    }
}

// ---------------------------------------------------------------------------
// Transposed-score fp16 MFMA flash attention, NO max tracking.
// R13 change: PAIRED q-tiles (pr, NT-1-pr) per block — every block does
// exactly 33 tile-iters (uniform), 512 blocks = exactly 2/CU, zero tail
// imbalance (R13 measured 25% time-avg occupancy on the 1024-block
// triangular grid: long-tq blocks dominated the drain). Internals are
// byte-identical to R12's single-buffered swizzled version (attn-dbuf
// regressed in R13 and is reverted). LDS 24 KB.
// ---------------------------------------------------------------------------
__global__ __launch_bounds__(256)
void attn_mfma(const u16* __restrict__ QP, const u16* __restrict__ KP,
               const u16* __restrict__ VT, const float* __restrict__ SUF,
               float* __restrict__ OUT)
{
    const int pr = blockIdx.x;          // 0..15
    const int bh = blockIdx.y;
    const int b  = bh >> 4, h = bh & 15;

    __shared__ u16 Ks[64 * 64];       // [key][d]   fp16, swizzled slots
    __shared__ u16 Vth[64 * 64];      // [vd][key]  fp16, swizzled slots
    __shared__ u16 Phi[4 * 16 * 64];  // [wave][q][key] fp16, swizzled slots

    const int tid  = threadIdx.x;
    const int w    = tid >> 6;
    const int lane = tid & 63;
    const int quad = lane >> 4;
    const int lr   = lane & 15;
    const int r    = tid >> 2;          // stage row 0..63
    const int q4   = tid & 3;           // stage col quarter (2 slots)

    const u16* Qb = QP + (size_t)bh * S_ * HD_;
    const u16* Kb = KP + (size_t)bh * S_ * HD_;
    const u16* Vb = VT + (size_t)bh * HD_ * S_;

    // swizzled LDS write offsets for the 2 chunks this thread stages
    int soff[2];
    #pragma unroll
    for (int c = 0; c < 2; ++c)
        soff[c] = r * 64 + (((q4 * 2 + c) ^ (r & 7)) << 3);

    for (int sub = 0; sub < 2; ++sub) {
        const int tq = sub ? (NT_ - 1 - pr) : pr;
        const int q0 = tq * 64;

        f16x8 qf[2];
        #pragma unroll
        for (int ch = 0; ch < 2; ++ch)
            qf[ch] = *(const f16x8*)(Qb + (size_t)(q0 + w * 16 + lr) * HD_ +
                                     ch * 32 + quad * 8);

        f32x4 of[4];
        #pragma unroll
        for (int n = 0; n < 4; ++n) of[n] = (f32x4){0.f, 0.f, 0.f, 0.f};
        float l_i = 0.f;

        f16x8 kpre[2], vpre[2];
        #pragma unroll
        for (int c = 0; c < 2; ++c) {
            kpre[c] = *(const f16x8*)(Kb + (size_t)r * HD_ + q4 * 16 + c * 8);
            vpre[c] = *(const f16x8*)(Vb + (size_t)r * S_ + q4 * 16 + c * 8);
        }

        for (int t = 0; t <= tq; ++t) {
            const int k0t = t * 64;
            __syncthreads();   // (A) prior iteration's tile reads done
            #pragma unroll
            for (int c = 0; c < 2; ++c) {
                *(f16x8*)&Ks[soff[c]]  = kpre[c];
                *(f16x8*)&Vth[soff[c]] = vpre[c];
            }
            __syncthreads();   // (B) tiles visible
            if (t < tq) {
                const int kn = k0t + 64;
                #pragma unroll
                for (int c = 0; c < 2; ++c) {
                    kpre[c] = *(const f16x8*)(Kb + (size_t)(kn + r) * HD_ + q4 * 16 + c * 8);
                    vpre[c] = *(const f16x8*)(Vb + (size_t)r * S_ + kn + q4 * 16 + c * 8);
                }
            }

            // ---- S^T = K Q^T (already in log2 domain; Q pre-scaled) ----
            f32x4 sf[4];
            #pragma unroll
            for (int f = 0; f < 4; ++f) sf[f] = (f32x4){0.f, 0.f, 0.f, 0.f};
            #pragma unroll
            for (int ch = 0; ch < 2; ++ch)
                #pragma unroll
                for (int f = 0; f < 4; ++f) {
                    f16x8 ak = *(const f16x8*)
                        &Ks[(f * 16 + lr) * 64 + (((ch * 4 + quad) ^ (lr & 7)) << 3)];
                    sf[f] = __builtin_amdgcn_mfma_f32_16x16x32_f16(ak, qf[ch], sf[f], 0, 0, 0);
                }

            // ---- zero-mask (diagonal tile only; reference zeroes pre-softmax) ----
            if (t == tq) {
                const int ig = q0 + w * 16 + lr;
                #pragma unroll
                for (int f = 0; f < 4; ++f)
                    #pragma unroll
                    for (int i = 0; i < 4; ++i) {
                        int jg = k0t + f * 16 + quad * 4 + i;
                        sf[f][i] = (jg <= ig) ? sf[f][i] : 0.f;
                    }
            }

            // ---- softmax numerators, no max subtraction ----
            float ps = 0.f;
            #pragma unroll
            for (int f = 0; f < 4; ++f)
                #pragma unroll
                for (int i = 0; i < 4; ++i) {
                    float p = exp2f(sf[f][i]);
                    sf[f][i] = p;
                    ps += p;
                }
            ps += __shfl_xor(ps, 16);
            ps += __shfl_xor(ps, 32);
            l_i += ps;

            // ---- P -> LDS as fp16 (one 8B write per frag; swizzled slot) ----
            #pragma unroll
            for (int f = 0; f < 4; ++f) {
                uint2 pw = make_uint2(pkrtz(sf[f][0], sf[f][1]),
                                      pkrtz(sf[f][2], sf[f][3]));
                *(uint2*)&Phi[(w * 16 + lr) * 64 +
                              (((f * 2 + (quad >> 1)) ^ (lr & 7)) << 3) +
                              (quad & 1) * 4] = pw;
            }

            // ---- O^T += V^T P^T  (in-wave LDS ordering; no barrier) ----
            #pragma unroll
            for (int ch = 0; ch < 2; ++ch) {
                f16x8 pb = *(const f16x8*)
                    &Phi[(w * 16 + lr) * 64 + (((ch * 4 + quad) ^ (lr & 7)) << 3)];
                #pragma unroll
                for (int n = 0; n < 4; ++n) {
                    f16x8 av = *(const f16x8*)
                        &Vth[(n * 16 + lr) * 64 + (((ch * 4 + quad) ^ (lr & 7)) << 3)];
                    of[n] = __builtin_amdgcn_mfma_f32_16x16x32_f16(av, pb, of[n], 0, 0, 0);
                }
            }
        }

        // ---- masked-suffix contribution (weight 1) + normalize + store ----
        const int cnt = S_ - (q0 + 64);
        const float* suf = SUF + ((size_t)bh * (NT_ + 1) + (tq + 1)) * HD_;
        float inv = 1.0f / (l_i + (float)cnt);
        const int srow = q0 + w * 16 + lr;
        #pragma unroll
        for (int n = 0; n < 4; ++n) {
            float4 sv = *(const float4*)&suf[n * 16 + quad * 4];
            float4 ov;
            ov.x = (of[n][0] + sv.x) * inv;
            ov.y = (of[n][1] + sv.y) * inv;
            ov.z = (of[n][2] + sv.z) * inv;
            ov.w = (of[n][3] + sv.w) * inv;
            *(float4*)&OUT[((size_t)b * S_ + srow) * D_ + h * HD_ + n * 16 + quad * 4] = ov;
        }
    }
}

// ---------------------------------------------------------------------------
extern "C" void kernel_launch(void* const* d_in, const int* in_sizes, int n_in,
                              void* d_out, int out_size, void* d_ws, size_t ws_size,
                              hipStream_t stream)
{
    (void)in_sizes; (void)n_in; (void)out_size; (void)ws_size;
    const float* q  = (const float*)d_in[0];
    const float* k  = (const float*)d_in[1];
    const float* v  = (const float*)d_in[2];
    const float* wq = (const float*)d_in[3];
    const float* wk = (const float*)d_in[4];
    const float* wv = (const float*)d_in[5];
    float* out = (float*)d_out;

    const size_t PROJ = (size_t)B_ * H_ * S_ * HD_;     // 4,194,304 elems
    const size_t WSZ  = (size_t)D_ * D_;                // 1,048,576 elems
    u16* QP = (u16*)d_ws;
    u16* KP = QP + PROJ;
    u16* VT = KP + PROJ;
    u16* Xq = VT + PROJ;
    u16* Xk = Xq + PROJ;
    u16* Xv = Xk + PROJ;
    u16* Wq = Xv + PROJ;
    u16* Wk = Wq + WSZ;
    u16* Wv = Wk + WSZ;
    float* TS  = (float*)(Wv + WSZ);
    float* SUF = TS + (size_t)B_ * H_ * NT_ * HD_;

    precast<<<dim3(PROJ / 1024, 6), 256, 0, stream>>>(
        wq, wk, wv, q, k, v, Wq, Wk, Wv, Xq, Xk, Xv);
    proj_all<<<dim3(3 * (D_ / 128) * ((B_ * S_) / 128)), 256, 0, stream>>>(
        Xq, Xk, Xv, Wq, Wk, Wv, QP, KP, VT);
    vtilesum_kernel<<<dim3(NT_, B_ * H_), 64, 0, stream>>>(VT, TS);
    vsuffix_kernel<<<B_ * H_, 64, 0, stream>>>(TS, SUF);
    attn_mfma<<<dim3(NT_ / 2, B_ * H_), 256, 0, stream>>>(QP, KP, VT, SUF, out);
}

// Round 15
// 193.194 us; speedup vs baseline: 1.0181x; 1.0181x over previous
//
#include <hip/hip_runtime.h>
#include <math.h>

#define B_  2
#define S_  2048
#define D_  1024
#define H_  16
#define HD_ 64
#define NT_ (S_/64)          // 32 key tiles
#define C2_ (0.125f * 1.44269504088896f)   // scale * log2(e)

typedef __attribute__((ext_vector_type(8))) _Float16 f16x8;
typedef __attribute__((ext_vector_type(2))) __fp16 h16x2;   // cvt_pkrtz return type
typedef __attribute__((ext_vector_type(4))) float f32x4;
typedef unsigned short u16;
typedef unsigned int   u32;

__device__ inline u16 f2h(float f) {             // RNE fp32->fp16 (HW cvt)
    union { _Float16 h; u16 u; } c; c.h = (_Float16)f;
    return c.u;
}
__device__ inline u32 pkrtz(float a, float b) {  // 1-inst pack: v_cvt_pkrtz_f16_f32
    union { h16x2 h; u32 u; } c;
    c.h = __builtin_amdgcn_cvt_pkrtz(a, b);
    return c.u;
}

// async global->LDS, 16 B per lane (dest = wave-uniform base + lane*16)
#define GLOAD_LDS16(g, l)                                                    \
    __builtin_amdgcn_global_load_lds(                                        \
        (const __attribute__((address_space(1))) void*)(g),                  \
        (__attribute__((address_space(3))) void*)(l), 16, 0, 0)

// ---------------------------------------------------------------------------
// Pre-cast all six tensors to fp16. z: 0=wq 1=wk 2=wv 3=q 4=k 5=v
// ---------------------------------------------------------------------------
__global__ __launch_bounds__(256)
void precast(const float* __restrict__ wq, const float* __restrict__ wk,
             const float* __restrict__ wv, const float* __restrict__ q,
             const float* __restrict__ k,  const float* __restrict__ v,
             u16* __restrict__ Wq, u16* __restrict__ Wk, u16* __restrict__ Wv,
             u16* __restrict__ Xq, u16* __restrict__ Xk, u16* __restrict__ Xv)
{
    const int z = blockIdx.y;
    const size_t n = (z >= 3) ? (size_t)B_ * S_ * D_ : (size_t)D_ * D_;
    const size_t i = ((size_t)blockIdx.x * 256 + threadIdx.x) * 4;
    if (i >= n) return;
    const float* src = (z == 0) ? wq : (z == 1) ? wk : (z == 2) ? wv
                     : (z == 3) ? q  : (z == 4) ? k  : v;
    u16* dst = (z == 0) ? Wq : (z == 1) ? Wk : (z == 2) ? Wv
             : (z == 3) ? Xq : (z == 4) ? Xk : Xv;
    float4 xv = *(const float4*)&src[i];
    *(ushort4*)&dst[i] = make_ushort4(f2h(xv.x), f2h(xv.y), f2h(xv.z), f2h(xv.w));
}

// ---------------------------------------------------------------------------
// Unified projection GEMM, fp16 — 128x128 tile, 4 waves (2M x 2N), BK=64,
// double-buffered counted-vmcnt pipeline (R12 best: 44.5 us). Unchanged.
// ---------------------------------------------------------------------------
__global__ __launch_bounds__(256, 2)
void proj_all(const u16* __restrict__ Xq, const u16* __restrict__ Xk,
              const u16* __restrict__ Xv, const u16* __restrict__ Wq,
              const u16* __restrict__ Wk, const u16* __restrict__ Wv,
              u16* __restrict__ QP, u16* __restrict__ KP, u16* __restrict__ VT)
{
    const int bid = (int)blockIdx.x;              // 0..767
    const int g   = (bid & 7) * 96 + (bid >> 3);  // bijective XCD chunking
    const int z   = g >> 8;                       // 0..2
    const int rem = g & 255;
    const int ny  = rem >> 3;                     // 0..31 (m panel)
    const int nx  = rem & 7;                      // 0..7  (n panel, fastest)

    const u16* X = (z == 0) ? Xq : (z == 1) ? Xk : Xv;
    const u16* W = (z == 0) ? Wq : (z == 1) ? Wk : Wv;

    __shared__ u16 Xs[2][128 * 64];   // linear [row][slot*8], swizzled content
    __shared__ u16 Ws[2][128 * 64];

    const int tid  = threadIdx.x;
    const int w    = tid >> 6;          // 0..3
    const int lane = tid & 63;
    const int quad = lane >> 4;
    const int lr   = lane & 15;
    const int wm   = w >> 1;            // 0..1 (M wave group)
    const int wn   = w & 1;             // 0..1 (N wave group)
    const int m0   = ny * 128;
    const int n0   = nx * 128;

    // --- staging geometry (per wave: 4 issues of 1 KB per matrix per buf) ---
    const int srow  = w * 32 + (lane >> 3);             // + c*8
    const int gslot = (lane & 7) ^ ((lane >> 3) & 7);   // inverse-swizzled src slot
    const size_t xbase = (size_t)(m0 + srow) * D_ + gslot * 8;
    const size_t wbase = (size_t)(n0 + srow) * D_ + gslot * 8;
    const int ldsoff = w * 2048 + lane * 8;             // + c*512 (elems)

    f32x4 acc[4][4];
    #pragma unroll
    for (int i = 0; i < 4; ++i)
        #pragma unroll
        for (int j = 0; j < 4; ++j) acc[i][j] = (f32x4){0.f, 0.f, 0.f, 0.f};

    // prologue: issue tile 0 into buffer 0 (8 loads outstanding)
    #pragma unroll
    for (int c = 0; c < 4; ++c) {
        GLOAD_LDS16(X + xbase + (size_t)c * 8 * D_, &Xs[0][ldsoff + c * 512]);
        GLOAD_LDS16(W + wbase + (size_t)c * 8 * D_, &Ws[0][ldsoff + c * 512]);
    }

    for (int t = 0; t < 16; ++t) {
        const int cur = t & 1;
        if (t < 15) {
            const size_t ko = (size_t)(t + 1) * 64;
            #pragma unroll
            for (int c = 0; c < 4; ++c) {
                GLOAD_LDS16(X + xbase + (size_t)c * 8 * D_ + ko,
                            &Xs[cur ^ 1][ldsoff + c * 512]);
                GLOAD_LDS16(W + wbase + (size_t)c * 8 * D_ + ko,
                            &Ws[cur ^ 1][ldsoff + c * 512]);
            }
            asm volatile("s_waitcnt vmcnt(8)" ::: "memory");
        } else {
            asm volatile("s_waitcnt vmcnt(0)" ::: "memory");
        }
        __builtin_amdgcn_s_barrier();   // (1) tile-t loads complete block-wide

        // ---- compute: 16 ds_read_b128 + 32 MFMA, compiler-interleaved ----
        f16x8 bf[4][2], af[4][2];
        #pragma unroll
        for (int fn = 0; fn < 4; ++fn) {
            const int row = wn * 64 + fn * 16 + lr;
            #pragma unroll
            for (int kk = 0; kk < 2; ++kk)
                bf[fn][kk] = *(const f16x8*)
                    &Ws[cur][row * 64 + (((kk * 4 + quad) ^ (lr & 7)) << 3)];
        }
        #pragma unroll
        for (int fm = 0; fm < 4; ++fm) {
            const int row = wm * 64 + fm * 16 + lr;
            #pragma unroll
            for (int kk = 0; kk < 2; ++kk)
                af[fm][kk] = *(const f16x8*)
                    &Xs[cur][row * 64 + (((kk * 4 + quad) ^ (lr & 7)) << 3)];
        }
        #pragma unroll
        for (int fm = 0; fm < 4; ++fm)
            #pragma unroll
            for (int fn = 0; fn < 4; ++fn)
                #pragma unroll
                for (int kk = 0; kk < 2; ++kk)
                    acc[fm][fn] = __builtin_amdgcn_mfma_f32_16x16x32_f16(
                        af[fm][kk], bf[fn][kk], acc[fm][fn], 0, 0, 0);
        __builtin_amdgcn_s_barrier();   // (2) reads of buf[cur] done before
                                        //     round t+1 re-stages into it
    }

    // ---- epilogue ----
    if (z < 2) {
        u16* P = (z == 0) ? QP : KP;
        const float sc = (z == 0) ? C2_ : 1.0f;   // fold softmax scale into Q
        #pragma unroll
        for (int fm = 0; fm < 4; ++fm)
            #pragma unroll
            for (int fn = 0; fn < 4; ++fn) {
                int n = n0 + wn * 64 + fn * 16 + lr;
                int h = n >> 6, hd = n & 63;
                #pragma unroll
                for (int r = 0; r < 4; ++r) {
                    int m = m0 + wm * 64 + fm * 16 + quad * 4 + r;
                    int b = m >> 11, s = m & (S_ - 1);
                    P[(((size_t)b * H_ + h) * S_ + s) * HD_ + hd] =
                        f2h(acc[fm][fn][r] * sc);
                }
            }
    } else {
        #pragma unroll
        for (int fm = 0; fm < 4; ++fm)
            #pragma unroll
            for (int fn = 0; fn < 4; ++fn) {
                int n  = n0 + wn * 64 + fn * 16 + lr;
                int h  = n >> 6, vd = n & 63;
                int m  = m0 + wm * 64 + fm * 16 + quad * 4;   // 4 consecutive s
                int b  = m >> 11, s = m & (S_ - 1);
                ushort4 pv = make_ushort4(f2h(acc[fm][fn][0]), f2h(acc[fm][fn][1]),
                                          f2h(acc[fm][fn][2]), f2h(acc[fm][fn][3]));
                *(ushort4*)&VT[(((size_t)b * H_ + h) * HD_ + vd) * S_ + s] = pv;
            }
    }
}

// ---------------------------------------------------------------------------
// V tile sums (fp16 VT, vectorized 16B loads) + suffix sums
// ---------------------------------------------------------------------------
__global__ __launch_bounds__(64)
void vtilesum_kernel(const u16* __restrict__ VT, float* __restrict__ TS)
{
    const int t = blockIdx.x, bh = blockIdx.y, vd = threadIdx.x;
    const u16* p = VT + ((size_t)bh * HD_ + vd) * S_ + t * 64;
    float acc = 0.f;
    #pragma unroll
    for (int c = 0; c < 8; ++c) {
        f16x8 vv = *(const f16x8*)&p[c * 8];
        #pragma unroll
        for (int j = 0; j < 8; ++j) acc += (float)vv[j];
    }
    TS[((size_t)bh * NT_ + t) * HD_ + vd] = acc;
}

__global__ __launch_bounds__(64)
void vsuffix_kernel(const float* __restrict__ TS, float* __restrict__ SUF)
{
    const int bh = blockIdx.x, c = threadIdx.x;
    float acc = 0.f;
    SUF[((size_t)bh * (NT_ + 1) + NT_) * HD_ + c] = 0.f;
    for (int t = NT_ - 1; t >= 0; --t) {
        acc += TS[((size_t)bh * NT_ + t) * HD_ + c];
        SUF[((size_t)bh * (NT_ + 1) + t) * HD_ + c] = acc;
    }
}

// ---------------------------------------------------------------------------
// Transposed-score fp16 MFMA flash attention, NO max tracking.
// R14 change: paired q-tiles KEPT (uniform 33 iters/block) but the grid is
// flat 512 with id = pr*32 + bh -> id mod 8 = bh mod 8: each XCD owns 4
// heads whose K/V (2 MB) stays L2-resident. R14's dim3(NT/2, B*H) grid put
// pr fastest, destroying that affinity: FETCH 12.4 -> 122 MB (10x) and
// attn 44.5 -> 53.9 us. This isolates pairing with locality held fixed.
// Internals byte-identical to R12's single-buffered swizzled version.
// LDS 24 KB.
// ---------------------------------------------------------------------------
__global__ __launch_bounds__(256)
void attn_mfma(const u16* __restrict__ QP, const u16* __restrict__ KP,
               const u16* __restrict__ VT, const float* __restrict__ SUF,
               float* __restrict__ OUT)
{
    const int id = (int)blockIdx.x;     // 0..511
    const int bh = id & 31;             // XCD = id mod 8 = bh mod 8
    const int pr = id >> 5;             // 0..15
    const int b  = bh >> 4, h = bh & 15;

    __shared__ u16 Ks[64 * 64];       // [key][d]   fp16, swizzled slots
    __shared__ u16 Vth[64 * 64];      // [vd][key]  fp16, swizzled slots
    __shared__ u16 Phi[4 * 16 * 64];  // [wave][q][key] fp16, swizzled slots

    const int tid  = threadIdx.x;
    const int w    = tid >> 6;
    const int lane = tid & 63;
    const int quad = lane >> 4;
    const int lr   = lane & 15;
    const int r    = tid >> 2;          // stage row 0..63
    const int q4   = tid & 3;           // stage col quarter (2 slots)

    const u16* Qb = QP + (size_t)bh * S_ * HD_;
    const u16* Kb = KP + (size_t)bh * S_ * HD_;
    const u16* Vb = VT + (size_t)bh * HD_ * S_;

    // swizzled LDS write offsets for the 2 chunks this thread stages
    int soff[2];
    #pragma unroll
    for (int c = 0; c < 2; ++c)
        soff[c] = r * 64 + (((q4 * 2 + c) ^ (r & 7)) << 3);

    for (int sub = 0; sub < 2; ++sub) {
        const int tq = sub ? (NT_ - 1 - pr) : pr;
        const int q0 = tq * 64;

        f16x8 qf[2];
        #pragma unroll
        for (int ch = 0; ch < 2; ++ch)
            qf[ch] = *(const f16x8*)(Qb + (size_t)(q0 + w * 16 + lr) * HD_ +
                                     ch * 32 + quad * 8);

        f32x4 of[4];
        #pragma unroll
        for (int n = 0; n < 4; ++n) of[n] = (f32x4){0.f, 0.f, 0.f, 0.f};
        float l_i = 0.f;

        f16x8 kpre[2], vpre[2];
        #pragma unroll
        for (int c = 0; c < 2; ++c) {
            kpre[c] = *(const f16x8*)(Kb + (size_t)r * HD_ + q4 * 16 + c * 8);
            vpre[c] = *(const f16x8*)(Vb + (size_t)r * S_ + q4 * 16 + c * 8);
        }

        for (int t = 0; t <= tq; ++t) {
            const int k0t = t * 64;
            __syncthreads();   // (A) prior iteration's tile reads done
            #pragma unroll
            for (int c = 0; c < 2; ++c) {
                *(f16x8*)&Ks[soff[c]]  = kpre[c];
                *(f16x8*)&Vth[soff[c]] = vpre[c];
            }
            __syncthreads();   // (B) tiles visible
            if (t < tq) {
                const int kn = k0t + 64;
                #pragma unroll
                for (int c = 0; c < 2; ++c) {
                    kpre[c] = *(const f16x8*)(Kb + (size_t)(kn + r) * HD_ + q4 * 16 + c * 8);
                    vpre[c] = *(const f16x8*)(Vb + (size_t)r * S_ + kn + q4 * 16 + c * 8);
                }
            }

            // ---- S^T = K Q^T (already in log2 domain; Q pre-scaled) ----
            f32x4 sf[4];
            #pragma unroll
            for (int f = 0; f < 4; ++f) sf[f] = (f32x4){0.f, 0.f, 0.f, 0.f};
            #pragma unroll
            for (int ch = 0; ch < 2; ++ch)
                #pragma unroll
                for (int f = 0; f < 4; ++f) {
                    f16x8 ak = *(const f16x8*)
                        &Ks[(f * 16 + lr) * 64 + (((ch * 4 + quad) ^ (lr & 7)) << 3)];
                    sf[f] = __builtin_amdgcn_mfma_f32_16x16x32_f16(ak, qf[ch], sf[f], 0, 0, 0);
                }

            // ---- zero-mask (diagonal tile only; reference zeroes pre-softmax) ----
            if (t == tq) {
                const int ig = q0 + w * 16 + lr;
                #pragma unroll
                for (int f = 0; f < 4; ++f)
                    #pragma unroll
                    for (int i = 0; i < 4; ++i) {
                        int jg = k0t + f * 16 + quad * 4 + i;
                        sf[f][i] = (jg <= ig) ? sf[f][i] : 0.f;
                    }
            }

            // ---- softmax numerators, no max subtraction ----
            float ps = 0.f;
            #pragma unroll
            for (int f = 0; f < 4; ++f)
                #pragma unroll
                for (int i = 0; i < 4; ++i) {
                    float p = exp2f(sf[f][i]);
                    sf[f][i] = p;
                    ps += p;
                }
            ps += __shfl_xor(ps, 16);
            ps += __shfl_xor(ps, 32);
            l_i += ps;

            // ---- P -> LDS as fp16 (one 8B write per frag; swizzled slot) ----
            #pragma unroll
            for (int f = 0; f < 4; ++f) {
                uint2 pw = make_uint2(pkrtz(sf[f][0], sf[f][1]),
                                      pkrtz(sf[f][2], sf[f][3]));
                *(uint2*)&Phi[(w * 16 + lr) * 64 +
                              (((f * 2 + (quad >> 1)) ^ (lr & 7)) << 3) +
                              (quad & 1) * 4] = pw;
            }

            // ---- O^T += V^T P^T  (in-wave LDS ordering; no barrier) ----
            #pragma unroll
            for (int ch = 0; ch < 2; ++ch) {
                f16x8 pb = *(const f16x8*)
                    &Phi[(w * 16 + lr) * 64 + (((ch * 4 + quad) ^ (lr & 7)) << 3)];
                #pragma unroll
                for (int n = 0; n < 4; ++n) {
                    f16x8 av = *(const f16x8*)
                        &Vth[(n * 16 + lr) * 64 + (((ch * 4 + quad) ^ (lr & 7)) << 3)];
                    of[n] = __builtin_amdgcn_mfma_f32_16x16x32_f16(av, pb, of[n], 0, 0, 0);
                }
            }
        }

        // ---- masked-suffix contribution (weight 1) + normalize + store ----
        const int cnt = S_ - (q0 + 64);
        const float* suf = SUF + ((size_t)bh * (NT_ + 1) + (tq + 1)) * HD_;
        float inv = 1.0f / (l_i + (float)cnt);
        const int srow = q0 + w * 16 + lr;
        #pragma unroll
        for (int n = 0; n < 4; ++n) {
            float4 sv = *(const float4*)&suf[n * 16 + quad * 4];
            float4 ov;
            ov.x = (of[n][0] + sv.x) * inv;
            ov.y = (of[n][1] + sv.y) * inv;
            ov.z = (of[n][2] + sv.z) * inv;
            ov.w = (of[n][3] + sv.w) * inv;
            *(float4*)&OUT[((size_t)b * S_ + srow) * D_ + h * HD_ + n * 16 + quad * 4] = ov;
        }
    }
}

// ---------------------------------------------------------------------------
extern "C" void kernel_launch(void* const* d_in, const int* in_sizes, int n_in,
                              void* d_out, int out_size, void* d_ws, size_t ws_size,
                              hipStream_t stream)
{
    (void)in_sizes; (void)n_in; (void)out_size; (void)ws_size;
    const float* q  = (const float*)d_in[0];
    const float* k  = (const float*)d_in[1];
    const float* v  = (const float*)d_in[2];
    const float* wq = (const float*)d_in[3];
    const float* wk = (const float*)d_in[4];
    const float* wv = (const float*)d_in[5];
    float* out = (float*)d_out;

    const size_t PROJ = (size_t)B_ * H_ * S_ * HD_;     // 4,194,304 elems
    const size_t WSZ  = (size_t)D_ * D_;                // 1,048,576 elems
    u16* QP = (u16*)d_ws;
    u16* KP = QP + PROJ;
    u16* VT = KP + PROJ;
    u16* Xq = VT + PROJ;
    u16* Xk = Xq + PROJ;
    u16* Xv = Xk + PROJ;
    u16* Wq = Xv + PROJ;
    u16* Wk = Wq + WSZ;
    u16* Wv = Wk + WSZ;
    float* TS  = (float*)(Wv + WSZ);
    float* SUF = TS + (size_t)B_ * H_ * NT_ * HD_;

    precast<<<dim3(PROJ / 1024, 6), 256, 0, stream>>>(
        wq, wk, wv, q, k, v, Wq, Wk, Wv, Xq, Xk, Xv);
    proj_all<<<dim3(3 * (D_ / 128) * ((B_ * S_) / 128)), 256, 0, stream>>>(
        Xq, Xk, Xv, Wq, Wk, Wv, QP, KP, VT);
    vtilesum_kernel<<<dim3(NT_, B_ * H_), 64, 0, stream>>>(VT, TS);
    vsuffix_kernel<<<B_ * H_, 64, 0, stream>>>(TS, SUF);
    attn_mfma<<<dim3((NT_ / 2) * B_ * H_), 256, 0, stream>>>(QP, KP, VT, SUF, out);
}

// Round 16
// 186.284 us; speedup vs baseline: 1.0558x; 1.0371x over previous
//
#include <hip/hip_runtime.h>
#include <math.h>

#define B_  2
#define S_  2048
#define D_  1024
#define H_  16
#define HD_ 64
#define NT_ (S_/64)          // 32 key tiles
#define C2_ (0.125f * 1.44269504088896f)   // scale * log2(e)

typedef __attribute__((ext_vector_type(8))) _Float16 f16x8;
typedef __attribute__((ext_vector_type(2))) __fp16 h16x2;   // cvt_pkrtz return type
typedef __attribute__((ext_vector_type(4))) float f32x4;
typedef unsigned short u16;
typedef unsigned int   u32;

__device__ inline u16 f2h(float f) {             // RNE fp32->fp16 (HW cvt)
    union { _Float16 h; u16 u; } c; c.h = (_Float16)f;
    return c.u;
}
__device__ inline u32 pkrtz(float a, float b) {  // 1-inst pack: v_cvt_pkrtz_f16_f32
    union { h16x2 h; u32 u; } c;
    c.h = __builtin_amdgcn_cvt_pkrtz(a, b);
    return c.u;
}

// async global->LDS, 16 B per lane (dest = wave-uniform base + lane*16)
#define GLOAD_LDS16(g, l)                                                    \
    __builtin_amdgcn_global_load_lds(                                        \
        (const __attribute__((address_space(1))) void*)(g),                  \
        (__attribute__((address_space(3))) void*)(l), 16, 0, 0)

// ---------------------------------------------------------------------------
// Pre-cast all six tensors to fp16. z: 0=wq 1=wk 2=wv 3=q 4=k 5=v
// ---------------------------------------------------------------------------
__global__ __launch_bounds__(256)
void precast(const float* __restrict__ wq, const float* __restrict__ wk,
             const float* __restrict__ wv, const float* __restrict__ q,
             const float* __restrict__ k,  const float* __restrict__ v,
             u16* __restrict__ Wq, u16* __restrict__ Wk, u16* __restrict__ Wv,
             u16* __restrict__ Xq, u16* __restrict__ Xk, u16* __restrict__ Xv)
{
    const int z = blockIdx.y;
    const size_t n = (z >= 3) ? (size_t)B_ * S_ * D_ : (size_t)D_ * D_;
    const size_t i = ((size_t)blockIdx.x * 256 + threadIdx.x) * 4;
    if (i >= n) return;
    const float* src = (z == 0) ? wq : (z == 1) ? wk : (z == 2) ? wv
                     : (z == 3) ? q  : (z == 4) ? k  : v;
    u16* dst = (z == 0) ? Wq : (z == 1) ? Wk : (z == 2) ? Wv
             : (z == 3) ? Xq : (z == 4) ? Xk : Xv;
    float4 xv = *(const float4*)&src[i];
    *(ushort4*)&dst[i] = make_ushort4(f2h(xv.x), f2h(xv.y), f2h(xv.z), f2h(xv.w));
}

// ---------------------------------------------------------------------------
// Unified projection GEMM, fp16 — 128x128 tile, 4 waves (2M x 2N), BK=64,
// double-buffered counted-vmcnt pipeline (R12 best: 44.5 us). Unchanged.
// ---------------------------------------------------------------------------
__global__ __launch_bounds__(256, 2)
void proj_all(const u16* __restrict__ Xq, const u16* __restrict__ Xk,
              const u16* __restrict__ Xv, const u16* __restrict__ Wq,
              const u16* __restrict__ Wk, const u16* __restrict__ Wv,
              u16* __restrict__ QP, u16* __restrict__ KP, u16* __restrict__ VT)
{
    const int bid = (int)blockIdx.x;              // 0..767
    const int g   = (bid & 7) * 96 + (bid >> 3);  // bijective XCD chunking
    const int z   = g >> 8;                       // 0..2
    const int rem = g & 255;
    const int ny  = rem >> 3;                     // 0..31 (m panel)
    const int nx  = rem & 7;                      // 0..7  (n panel, fastest)

    const u16* X = (z == 0) ? Xq : (z == 1) ? Xk : Xv;
    const u16* W = (z == 0) ? Wq : (z == 1) ? Wk : Wv;

    __shared__ u16 Xs[2][128 * 64];   // linear [row][slot*8], swizzled content
    __shared__ u16 Ws[2][128 * 64];

    const int tid  = threadIdx.x;
    const int w    = tid >> 6;          // 0..3
    const int lane = tid & 63;
    const int quad = lane >> 4;
    const int lr   = lane & 15;
    const int wm   = w >> 1;            // 0..1 (M wave group)
    const int wn   = w & 1;             // 0..1 (N wave group)
    const int m0   = ny * 128;
    const int n0   = nx * 128;

    // --- staging geometry (per wave: 4 issues of 1 KB per matrix per buf) ---
    const int srow  = w * 32 + (lane >> 3);             // + c*8
    const int gslot = (lane & 7) ^ ((lane >> 3) & 7);   // inverse-swizzled src slot
    const size_t xbase = (size_t)(m0 + srow) * D_ + gslot * 8;
    const size_t wbase = (size_t)(n0 + srow) * D_ + gslot * 8;
    const int ldsoff = w * 2048 + lane * 8;             // + c*512 (elems)

    f32x4 acc[4][4];
    #pragma unroll
    for (int i = 0; i < 4; ++i)
        #pragma unroll
        for (int j = 0; j < 4; ++j) acc[i][j] = (f32x4){0.f, 0.f, 0.f, 0.f};

    // prologue: issue tile 0 into buffer 0 (8 loads outstanding)
    #pragma unroll
    for (int c = 0; c < 4; ++c) {
        GLOAD_LDS16(X + xbase + (size_t)c * 8 * D_, &Xs[0][ldsoff + c * 512]);
        GLOAD_LDS16(W + wbase + (size_t)c * 8 * D_, &Ws[0][ldsoff + c * 512]);
    }

    for (int t = 0; t < 16; ++t) {
        const int cur = t & 1;
        if (t < 15) {
            const size_t ko = (size_t)(t + 1) * 64;
            #pragma unroll
            for (int c = 0; c < 4; ++c) {
                GLOAD_LDS16(X + xbase + (size_t)c * 8 * D_ + ko,
                            &Xs[cur ^ 1][ldsoff + c * 512]);
                GLOAD_LDS16(W + wbase + (size_t)c * 8 * D_ + ko,
                            &Ws[cur ^ 1][ldsoff + c * 512]);
            }
            asm volatile("s_waitcnt vmcnt(8)" ::: "memory");
        } else {
            asm volatile("s_waitcnt vmcnt(0)" ::: "memory");
        }
        __builtin_amdgcn_s_barrier();   // (1) tile-t loads complete block-wide

        // ---- compute: 16 ds_read_b128 + 32 MFMA, compiler-interleaved ----
        f16x8 bf[4][2], af[4][2];
        #pragma unroll
        for (int fn = 0; fn < 4; ++fn) {
            const int row = wn * 64 + fn * 16 + lr;
            #pragma unroll
            for (int kk = 0; kk < 2; ++kk)
                bf[fn][kk] = *(const f16x8*)
                    &Ws[cur][row * 64 + (((kk * 4 + quad) ^ (lr & 7)) << 3)];
        }
        #pragma unroll
        for (int fm = 0; fm < 4; ++fm) {
            const int row = wm * 64 + fm * 16 + lr;
            #pragma unroll
            for (int kk = 0; kk < 2; ++kk)
                af[fm][kk] = *(const f16x8*)
                    &Xs[cur][row * 64 + (((kk * 4 + quad) ^ (lr & 7)) << 3)];
        }
        #pragma unroll
        for (int fm = 0; fm < 4; ++fm)
            #pragma unroll
            for (int fn = 0; fn < 4; ++fn)
                #pragma unroll
                for (int kk = 0; kk < 2; ++kk)
                    acc[fm][fn] = __builtin_amdgcn_mfma_f32_16x16x32_f16(
                        af[fm][kk], bf[fn][kk], acc[fm][fn], 0, 0, 0);
        __builtin_amdgcn_s_barrier();   // (2) reads of buf[cur] done before
                                        //     round t+1 re-stages into it
    }

    // ---- epilogue ----
    if (z < 2) {
        u16* P = (z == 0) ? QP : KP;
        const float sc = (z == 0) ? C2_ : 1.0f;   // fold softmax scale into Q
        #pragma unroll
        for (int fm = 0; fm < 4; ++fm)
            #pragma unroll
            for (int fn = 0; fn < 4; ++fn) {
                int n = n0 + wn * 64 + fn * 16 + lr;
                int h = n >> 6, hd = n & 63;
                #pragma unroll
                for (int r = 0; r < 4; ++r) {
                    int m = m0 + wm * 64 + fm * 16 + quad * 4 + r;
                    int b = m >> 11, s = m & (S_ - 1);
                    P[(((size_t)b * H_ + h) * S_ + s) * HD_ + hd] =
                        f2h(acc[fm][fn][r] * sc);
                }
            }
    } else {
        #pragma unroll
        for (int fm = 0; fm < 4; ++fm)
            #pragma unroll
            for (int fn = 0; fn < 4; ++fn) {
                int n  = n0 + wn * 64 + fn * 16 + lr;
                int h  = n >> 6, vd = n & 63;
                int m  = m0 + wm * 64 + fm * 16 + quad * 4;   // 4 consecutive s
                int b  = m >> 11, s = m & (S_ - 1);
                ushort4 pv = make_ushort4(f2h(acc[fm][fn][0]), f2h(acc[fm][fn][1]),
                                          f2h(acc[fm][fn][2]), f2h(acc[fm][fn][3]));
                *(ushort4*)&VT[(((size_t)b * H_ + h) * HD_ + vd) * S_ + s] = pv;
            }
    }
}

// ---------------------------------------------------------------------------
// V tile sums (fp16 VT, vectorized 16B loads) + suffix sums
// ---------------------------------------------------------------------------
__global__ __launch_bounds__(64)
void vtilesum_kernel(const u16* __restrict__ VT, float* __restrict__ TS)
{
    const int t = blockIdx.x, bh = blockIdx.y, vd = threadIdx.x;
    const u16* p = VT + ((size_t)bh * HD_ + vd) * S_ + t * 64;
    float acc = 0.f;
    #pragma unroll
    for (int c = 0; c < 8; ++c) {
        f16x8 vv = *(const f16x8*)&p[c * 8];
        #pragma unroll
        for (int j = 0; j < 8; ++j) acc += (float)vv[j];
    }
    TS[((size_t)bh * NT_ + t) * HD_ + vd] = acc;
}

__global__ __launch_bounds__(64)
void vsuffix_kernel(const float* __restrict__ TS, float* __restrict__ SUF)
{
    const int bh = blockIdx.x, c = threadIdx.x;
    float acc = 0.f;
    SUF[((size_t)bh * (NT_ + 1) + NT_) * HD_ + c] = 0.f;
    for (int t = NT_ - 1; t >= 0; --t) {
        acc += TS[((size_t)bh * NT_ + t) * HD_ + c];
        SUF[((size_t)bh * (NT_ + 1) + t) * HD_ + c] = acc;
    }
}

// ---------------------------------------------------------------------------
// Transposed-score fp16 MFMA flash attention, NO max tracking.
// R12 configuration restored (best measured): UNPAIRED grid dim3(B*H, NT),
// longest-first, 1024 blocks = 4/CU (R15 proved pairing costs TLP: 512
// blocks = 2/CU -> 50.6 us vs ~44 here, locality equal). The dim3 grid's
// blockIdx.x = bh gives XCD = bh mod 8: each XCD owns 4 heads' K/V (2 MB,
// L2-resident; FETCH 12.4 MB). Single-buffered swizzled LDS (dbuf
// regressed, R13). Ks/Vth/Phi linear [.][64] with 16B-slot XOR swizzle
// (slot ^= row&7) on write and read. LDS 24 KB.
// ---------------------------------------------------------------------------
__global__ __launch_bounds__(256)
void attn_mfma(const u16* __restrict__ QP, const u16* __restrict__ KP,
               const u16* __restrict__ VT, const float* __restrict__ SUF,
               float* __restrict__ OUT)
{
    const int bh = blockIdx.x;
    const int tq = NT_ - 1 - (int)blockIdx.y;   // longest blocks first
    const int b  = bh >> 4, h = bh & 15;

    __shared__ u16 Ks[64 * 64];       // [key][d]   fp16, swizzled slots
    __shared__ u16 Vth[64 * 64];      // [vd][key]  fp16, swizzled slots
    __shared__ u16 Phi[4 * 16 * 64];  // [wave][q][key] fp16, swizzled slots

    const int tid  = threadIdx.x;
    const int w    = tid >> 6;
    const int lane = tid & 63;
    const int quad = lane >> 4;
    const int lr   = lane & 15;
    const int r    = tid >> 2;          // stage row 0..63
    const int q4   = tid & 3;           // stage col quarter (2 slots)

    const u16* Qb = QP + (size_t)bh * S_ * HD_;
    const u16* Kb = KP + (size_t)bh * S_ * HD_;
    const u16* Vb = VT + (size_t)bh * HD_ * S_;

    const int q0 = tq * 64;

    f16x8 qf[2];
    #pragma unroll
    for (int ch = 0; ch < 2; ++ch)
        qf[ch] = *(const f16x8*)(Qb + (size_t)(q0 + w * 16 + lr) * HD_ +
                                 ch * 32 + quad * 8);

    f32x4 of[4];
    #pragma unroll
    for (int n = 0; n < 4; ++n) of[n] = (f32x4){0.f, 0.f, 0.f, 0.f};
    float l_i = 0.f;

    // swizzled LDS write offsets for the 2 chunks this thread stages
    int soff[2];
    #pragma unroll
    for (int c = 0; c < 2; ++c)
        soff[c] = r * 64 + (((q4 * 2 + c) ^ (r & 7)) << 3);

    f16x8 kpre[2], vpre[2];
    #pragma unroll
    for (int c = 0; c < 2; ++c) {
        kpre[c] = *(const f16x8*)(Kb + (size_t)r * HD_ + q4 * 16 + c * 8);
        vpre[c] = *(const f16x8*)(Vb + (size_t)r * S_ + q4 * 16 + c * 8);
    }

    for (int t = 0; t <= tq; ++t) {
        const int k0t = t * 64;
        __syncthreads();   // (A) prior iteration's tile reads done
        #pragma unroll
        for (int c = 0; c < 2; ++c) {
            *(f16x8*)&Ks[soff[c]]  = kpre[c];
            *(f16x8*)&Vth[soff[c]] = vpre[c];
        }
        __syncthreads();   // (B) tiles visible
        if (t < tq) {
            const int kn = k0t + 64;
            #pragma unroll
            for (int c = 0; c < 2; ++c) {
                kpre[c] = *(const f16x8*)(Kb + (size_t)(kn + r) * HD_ + q4 * 16 + c * 8);
                vpre[c] = *(const f16x8*)(Vb + (size_t)r * S_ + kn + q4 * 16 + c * 8);
            }
        }

        // ---- S^T = K Q^T (already in log2 domain; Q pre-scaled) ----
        f32x4 sf[4];
        #pragma unroll
        for (int f = 0; f < 4; ++f) sf[f] = (f32x4){0.f, 0.f, 0.f, 0.f};
        #pragma unroll
        for (int ch = 0; ch < 2; ++ch)
            #pragma unroll
            for (int f = 0; f < 4; ++f) {
                f16x8 ak = *(const f16x8*)
                    &Ks[(f * 16 + lr) * 64 + (((ch * 4 + quad) ^ (lr & 7)) << 3)];
                sf[f] = __builtin_amdgcn_mfma_f32_16x16x32_f16(ak, qf[ch], sf[f], 0, 0, 0);
            }

        // ---- zero-mask (diagonal tile only; reference zeroes pre-softmax) ----
        if (t == tq) {
            const int ig = q0 + w * 16 + lr;
            #pragma unroll
            for (int f = 0; f < 4; ++f)
                #pragma unroll
                for (int i = 0; i < 4; ++i) {
                    int jg = k0t + f * 16 + quad * 4 + i;
                    sf[f][i] = (jg <= ig) ? sf[f][i] : 0.f;
                }
        }

        // ---- softmax numerators, no max subtraction ----
        float ps = 0.f;
        #pragma unroll
        for (int f = 0; f < 4; ++f)
            #pragma unroll
            for (int i = 0; i < 4; ++i) {
                float p = exp2f(sf[f][i]);
                sf[f][i] = p;
                ps += p;
            }
        ps += __shfl_xor(ps, 16);
        ps += __shfl_xor(ps, 32);
        l_i += ps;

        // ---- P -> LDS as fp16 (one 8B write per frag; swizzled slot) ----
        #pragma unroll
        for (int f = 0; f < 4; ++f) {
            uint2 pw = make_uint2(pkrtz(sf[f][0], sf[f][1]),
                                  pkrtz(sf[f][2], sf[f][3]));
            *(uint2*)&Phi[(w * 16 + lr) * 64 +
                          (((f * 2 + (quad >> 1)) ^ (lr & 7)) << 3) +
                          (quad & 1) * 4] = pw;
        }

        // ---- O^T += V^T P^T  (in-wave LDS ordering; no barrier) ----
        #pragma unroll
        for (int ch = 0; ch < 2; ++ch) {
            f16x8 pb = *(const f16x8*)
                &Phi[(w * 16 + lr) * 64 + (((ch * 4 + quad) ^ (lr & 7)) << 3)];
            #pragma unroll
            for (int n = 0; n < 4; ++n) {
                f16x8 av = *(const f16x8*)
                    &Vth[(n * 16 + lr) * 64 + (((ch * 4 + quad) ^ (lr & 7)) << 3)];
                of[n] = __builtin_amdgcn_mfma_f32_16x16x32_f16(av, pb, of[n], 0, 0, 0);
            }
        }
    }

    // ---- masked-suffix contribution (weight 1) + normalize + store ----
    const int cnt = S_ - (q0 + 64);
    const float* suf = SUF + ((size_t)bh * (NT_ + 1) + (tq + 1)) * HD_;
    float inv = 1.0f / (l_i + (float)cnt);
    const int srow = q0 + w * 16 + lr;
    #pragma unroll
    for (int n = 0; n < 4; ++n) {
        float4 sv = *(const float4*)&suf[n * 16 + quad * 4];
        float4 ov;
        ov.x = (of[n][0] + sv.x) * inv;
        ov.y = (of[n][1] + sv.y) * inv;
        ov.z = (of[n][2] + sv.z) * inv;
        ov.w = (of[n][3] + sv.w) * inv;
        *(float4*)&OUT[((size_t)b * S_ + srow) * D_ + h * HD_ + n * 16 + quad * 4] = ov;
    }
}

// ---------------------------------------------------------------------------
extern "C" void kernel_launch(void* const* d_in, const int* in_sizes, int n_in,
                              void* d_out, int out_size, void* d_ws, size_t ws_size,
                              hipStream_t stream)
{
    (void)in_sizes; (void)n_in; (void)out_size; (void)ws_size;
    const float* q  = (const float*)d_in[0];
    const float* k  = (const float*)d_in[1];
    const float* v  = (const float*)d_in[2];
    const float* wq = (const float*)d_in[3];
    const float* wk = (const float*)d_in[4];
    const float* wv = (const float*)d_in[5];
    float* out = (float*)d_out;

    const size_t PROJ = (size_t)B_ * H_ * S_ * HD_;     // 4,194,304 elems
    const size_t WSZ  = (size_t)D_ * D_;                // 1,048,576 elems
    u16* QP = (u16*)d_ws;
    u16* KP = QP + PROJ;
    u16* VT = KP + PROJ;
    u16* Xq = VT + PROJ;
    u16* Xk = Xq + PROJ;
    u16* Xv = Xk + PROJ;
    u16* Wq = Xv + PROJ;
    u16* Wk = Wq + WSZ;
    u16* Wv = Wk + WSZ;
    float* TS  = (float*)(Wv + WSZ);
    float* SUF = TS + (size_t)B_ * H_ * NT_ * HD_;

    precast<<<dim3(PROJ / 1024, 6), 256, 0, stream>>>(
        wq, wk, wv, q, k, v, Wq, Wk, Wv, Xq, Xk, Xv);
    proj_all<<<dim3(3 * (D_ / 128) * ((B_ * S_) / 128)), 256, 0, stream>>>(
        Xq, Xk, Xv, Wq, Wk, Wv, QP, KP, VT);
    vtilesum_kernel<<<dim3(NT_, B_ * H_), 64, 0, stream>>>(VT, TS);
    vsuffix_kernel<<<B_ * H_, 64, 0, stream>>>(TS, SUF);
    attn_mfma<<<dim3(B_ * H_, NT_), 256, 0, stream>>>(QP, KP, VT, SUF, out);
}

// Round 17
// 178.509 us; speedup vs baseline: 1.1018x; 1.0436x over previous
//
#include <hip/hip_runtime.h>
#include <math.h>

#define B_  2
#define S_  2048
#define D_  1024
#define H_  16
#define HD_ 64
#define NT_ (S_/64)          // 32 key tiles
#define C2_ (0.125f * 1.44269504088896f)   // scale * log2(e)

typedef __attribute__((ext_vector_type(8))) _Float16 f16x8;
typedef __attribute__((ext_vector_type(2))) __fp16 h16x2;   // cvt_pkrtz return type
typedef __attribute__((ext_vector_type(4))) float f32x4;
typedef unsigned short u16;
typedef unsigned int   u32;

__device__ inline u16 f2h(float f) {             // RNE fp32->fp16 (HW cvt)
    union { _Float16 h; u16 u; } c; c.h = (_Float16)f;
    return c.u;
}
__device__ inline u32 pkrtz(float a, float b) {  // 1-inst pack: v_cvt_pkrtz_f16_f32
    union { h16x2 h; u32 u; } c;
    c.h = __builtin_amdgcn_cvt_pkrtz(a, b);
    return c.u;
}

// async global->LDS, 16 B per lane (dest = wave-uniform base + lane*16)
#define GLOAD_LDS16(g, l)                                                    \
    __builtin_amdgcn_global_load_lds(                                        \
        (const __attribute__((address_space(1))) void*)(g),                  \
        (__attribute__((address_space(3))) void*)(l), 16, 0, 0)

// ---------------------------------------------------------------------------
// Pre-cast all six tensors to fp16. z: 0=wq 1=wk 2=wv 3=q 4=k 5=v
// ---------------------------------------------------------------------------
__global__ __launch_bounds__(256)
void precast(const float* __restrict__ wq, const float* __restrict__ wk,
             const float* __restrict__ wv, const float* __restrict__ q,
             const float* __restrict__ k,  const float* __restrict__ v,
             u16* __restrict__ Wq, u16* __restrict__ Wk, u16* __restrict__ Wv,
             u16* __restrict__ Xq, u16* __restrict__ Xk, u16* __restrict__ Xv)
{
    const int z = blockIdx.y;
    const size_t n = (z >= 3) ? (size_t)B_ * S_ * D_ : (size_t)D_ * D_;
    const size_t i = ((size_t)blockIdx.x * 256 + threadIdx.x) * 4;
    if (i >= n) return;
    const float* src = (z == 0) ? wq : (z == 1) ? wk : (z == 2) ? wv
                     : (z == 3) ? q  : (z == 4) ? k  : v;
    u16* dst = (z == 0) ? Wq : (z == 1) ? Wk : (z == 2) ? Wv
             : (z == 3) ? Xq : (z == 4) ? Xk : Xv;
    float4 xv = *(const float4*)&src[i];
    *(ushort4*)&dst[i] = make_ushort4(f2h(xv.x), f2h(xv.y), f2h(xv.z), f2h(xv.w));
}

// ---------------------------------------------------------------------------
// Unified projection GEMM, fp16 — 128x128 tile, 4 waves (2M x 2N), BK=64,
// double-buffered counted-vmcnt pipeline (R12/R16 best: ~42 us).
// R16 change: the z==2 epilogue now also computes the V TILE-SUMS in-place
// (fused vtilesum): wave wm covers exactly tile t = 2*ny + wm (64 s), so
// p[fn] = sum_{fm,r} acc[fm][fn][r] + shfl_xor(16,32) across quads gives
// the full 64-s tile sum per vd; quad-0 lanes store TS. Removes the
// vtilesum launch + its 8 MB VT re-read; ~80 VALU ops in a latency-bound
// epilogue (VALUBusy 13.7% -> free). Race-free: each (bh,t,vd) belongs to
// exactly one block. Sums now fp32 (pre-cast) -- within tolerance.
// ---------------------------------------------------------------------------
__global__ __launch_bounds__(256, 2)
void proj_all(const u16* __restrict__ Xq, const u16* __restrict__ Xk,
              const u16* __restrict__ Xv, const u16* __restrict__ Wq,
              const u16* __restrict__ Wk, const u16* __restrict__ Wv,
              u16* __restrict__ QP, u16* __restrict__ KP, u16* __restrict__ VT,
              float* __restrict__ TS)
{
    const int bid = (int)blockIdx.x;              // 0..767
    const int g   = (bid & 7) * 96 + (bid >> 3);  // bijective XCD chunking
    const int z   = g >> 8;                       // 0..2
    const int rem = g & 255;
    const int ny  = rem >> 3;                     // 0..31 (m panel)
    const int nx  = rem & 7;                      // 0..7  (n panel, fastest)

    const u16* X = (z == 0) ? Xq : (z == 1) ? Xk : Xv;
    const u16* W = (z == 0) ? Wq : (z == 1) ? Wk : Wv;

    __shared__ u16 Xs[2][128 * 64];   // linear [row][slot*8], swizzled content
    __shared__ u16 Ws[2][128 * 64];

    const int tid  = threadIdx.x;
    const int w    = tid >> 6;          // 0..3
    const int lane = tid & 63;
    const int quad = lane >> 4;
    const int lr   = lane & 15;
    const int wm   = w >> 1;            // 0..1 (M wave group)
    const int wn   = w & 1;             // 0..1 (N wave group)
    const int m0   = ny * 128;
    const int n0   = nx * 128;

    // --- staging geometry (per wave: 4 issues of 1 KB per matrix per buf) ---
    const int srow  = w * 32 + (lane >> 3);             // + c*8
    const int gslot = (lane & 7) ^ ((lane >> 3) & 7);   // inverse-swizzled src slot
    const size_t xbase = (size_t)(m0 + srow) * D_ + gslot * 8;
    const size_t wbase = (size_t)(n0 + srow) * D_ + gslot * 8;
    const int ldsoff = w * 2048 + lane * 8;             // + c*512 (elems)

    f32x4 acc[4][4];
    #pragma unroll
    for (int i = 0; i < 4; ++i)
        #pragma unroll
        for (int j = 0; j < 4; ++j) acc[i][j] = (f32x4){0.f, 0.f, 0.f, 0.f};

    // prologue: issue tile 0 into buffer 0 (8 loads outstanding)
    #pragma unroll
    for (int c = 0; c < 4; ++c) {
        GLOAD_LDS16(X + xbase + (size_t)c * 8 * D_, &Xs[0][ldsoff + c * 512]);
        GLOAD_LDS16(W + wbase + (size_t)c * 8 * D_, &Ws[0][ldsoff + c * 512]);
    }

    for (int t = 0; t < 16; ++t) {
        const int cur = t & 1;
        if (t < 15) {
            const size_t ko = (size_t)(t + 1) * 64;
            #pragma unroll
            for (int c = 0; c < 4; ++c) {
                GLOAD_LDS16(X + xbase + (size_t)c * 8 * D_ + ko,
                            &Xs[cur ^ 1][ldsoff + c * 512]);
                GLOAD_LDS16(W + wbase + (size_t)c * 8 * D_ + ko,
                            &Ws[cur ^ 1][ldsoff + c * 512]);
            }
            asm volatile("s_waitcnt vmcnt(8)" ::: "memory");
        } else {
            asm volatile("s_waitcnt vmcnt(0)" ::: "memory");
        }
        __builtin_amdgcn_s_barrier();   // (1) tile-t loads complete block-wide

        // ---- compute: 16 ds_read_b128 + 32 MFMA, compiler-interleaved ----
        f16x8 bf[4][2], af[4][2];
        #pragma unroll
        for (int fn = 0; fn < 4; ++fn) {
            const int row = wn * 64 + fn * 16 + lr;
            #pragma unroll
            for (int kk = 0; kk < 2; ++kk)
                bf[fn][kk] = *(const f16x8*)
                    &Ws[cur][row * 64 + (((kk * 4 + quad) ^ (lr & 7)) << 3)];
        }
        #pragma unroll
        for (int fm = 0; fm < 4; ++fm) {
            const int row = wm * 64 + fm * 16 + lr;
            #pragma unroll
            for (int kk = 0; kk < 2; ++kk)
                af[fm][kk] = *(const f16x8*)
                    &Xs[cur][row * 64 + (((kk * 4 + quad) ^ (lr & 7)) << 3)];
        }
        #pragma unroll
        for (int fm = 0; fm < 4; ++fm)
            #pragma unroll
            for (int fn = 0; fn < 4; ++fn)
                #pragma unroll
                for (int kk = 0; kk < 2; ++kk)
                    acc[fm][fn] = __builtin_amdgcn_mfma_f32_16x16x32_f16(
                        af[fm][kk], bf[fn][kk], acc[fm][fn], 0, 0, 0);
        __builtin_amdgcn_s_barrier();   // (2) reads of buf[cur] done before
                                        //     round t+1 re-stages into it
    }

    // ---- epilogue ----
    if (z < 2) {
        u16* P = (z == 0) ? QP : KP;
        const float sc = (z == 0) ? C2_ : 1.0f;   // fold softmax scale into Q
        #pragma unroll
        for (int fm = 0; fm < 4; ++fm)
            #pragma unroll
            for (int fn = 0; fn < 4; ++fn) {
                int n = n0 + wn * 64 + fn * 16 + lr;
                int h = n >> 6, hd = n & 63;
                #pragma unroll
                for (int r = 0; r < 4; ++r) {
                    int m = m0 + wm * 64 + fm * 16 + quad * 4 + r;
                    int b = m >> 11, s = m & (S_ - 1);
                    P[(((size_t)b * H_ + h) * S_ + s) * HD_ + hd] =
                        f2h(acc[fm][fn][r] * sc);
                }
            }
    } else {
        #pragma unroll
        for (int fm = 0; fm < 4; ++fm)
            #pragma unroll
            for (int fn = 0; fn < 4; ++fn) {
                int n  = n0 + wn * 64 + fn * 16 + lr;
                int h  = n >> 6, vd = n & 63;
                int m  = m0 + wm * 64 + fm * 16 + quad * 4;   // 4 consecutive s
                int b  = m >> 11, s = m & (S_ - 1);
                ushort4 pv = make_ushort4(f2h(acc[fm][fn][0]), f2h(acc[fm][fn][1]),
                                          f2h(acc[fm][fn][2]), f2h(acc[fm][fn][3]));
                *(ushort4*)&VT[(((size_t)b * H_ + h) * HD_ + vd) * S_ + s] = pv;
            }

        // ---- fused V tile-sums: wave wm covers exactly tile tt = 2*ny+wm ----
        const int b  = m0 >> 11;
        const int tt = ((m0 & (S_ - 1)) >> 6) + wm;
        #pragma unroll
        for (int fn = 0; fn < 4; ++fn) {
            float p = 0.f;
            #pragma unroll
            for (int fm = 0; fm < 4; ++fm)
                #pragma unroll
                for (int r = 0; r < 4; ++r) p += acc[fm][fn][r];
            p += __shfl_xor(p, 16);     // sum across the 4 quads (64 s total)
            p += __shfl_xor(p, 32);
            if (quad == 0) {
                int n = n0 + wn * 64 + fn * 16 + lr;
                int h = n >> 6, vd = n & 63;
                TS[(((size_t)b * H_ + h) * NT_ + tt) * HD_ + vd] = p;
            }
        }
    }
}

// ---------------------------------------------------------------------------
// V suffix sums over TS (tiny; reads 0.5 MB)
// ---------------------------------------------------------------------------
__global__ __launch_bounds__(64)
void vsuffix_kernel(const float* __restrict__ TS, float* __restrict__ SUF)
{
    const int bh = blockIdx.x, c = threadIdx.x;
    float acc = 0.f;
    SUF[((size_t)bh * (NT_ + 1) + NT_) * HD_ + c] = 0.f;
    for (int t = NT_ - 1; t >= 0; --t) {
        acc += TS[((size_t)bh * NT_ + t) * HD_ + c];
        SUF[((size_t)bh * (NT_ + 1) + t) * HD_ + c] = acc;
    }
}

// ---------------------------------------------------------------------------
// Transposed-score fp16 MFMA flash attention, NO max tracking.
// R12/R16 best configuration: UNPAIRED grid dim3(B*H, NT), longest-first,
// 1024 blocks = 4/CU; blockIdx.x = bh gives XCD = bh mod 8 (each XCD owns
// 4 heads' K/V, 2 MB L2-resident; FETCH 12.4 MB). Single-buffered swizzled
// LDS. Ks/Vth/Phi linear [.][64] with 16B-slot XOR swizzle (slot ^= row&7)
// on write and read. LDS 24 KB. Unchanged.
// ---------------------------------------------------------------------------
__global__ __launch_bounds__(256)
void attn_mfma(const u16* __restrict__ QP, const u16* __restrict__ KP,
               const u16* __restrict__ VT, const float* __restrict__ SUF,
               float* __restrict__ OUT)
{
    const int bh = blockIdx.x;
    const int tq = NT_ - 1 - (int)blockIdx.y;   // longest blocks first
    const int b  = bh >> 4, h = bh & 15;

    __shared__ u16 Ks[64 * 64];       // [key][d]   fp16, swizzled slots
    __shared__ u16 Vth[64 * 64];      // [vd][key]  fp16, swizzled slots
    __shared__ u16 Phi[4 * 16 * 64];  // [wave][q][key] fp16, swizzled slots

    const int tid  = threadIdx.x;
    const int w    = tid >> 6;
    const int lane = tid & 63;
    const int quad = lane >> 4;
    const int lr   = lane & 15;
    const int r    = tid >> 2;          // stage row 0..63
    const int q4   = tid & 3;           // stage col quarter (2 slots)

    const u16* Qb = QP + (size_t)bh * S_ * HD_;
    const u16* Kb = KP + (size_t)bh * S_ * HD_;
    const u16* Vb = VT + (size_t)bh * HD_ * S_;

    const int q0 = tq * 64;

    f16x8 qf[2];
    #pragma unroll
    for (int ch = 0; ch < 2; ++ch)
        qf[ch] = *(const f16x8*)(Qb + (size_t)(q0 + w * 16 + lr) * HD_ +
                                 ch * 32 + quad * 8);

    f32x4 of[4];
    #pragma unroll
    for (int n = 0; n < 4; ++n) of[n] = (f32x4){0.f, 0.f, 0.f, 0.f};
    float l_i = 0.f;

    // swizzled LDS write offsets for the 2 chunks this thread stages
    int soff[2];
    #pragma unroll
    for (int c = 0; c < 2; ++c)
        soff[c] = r * 64 + (((q4 * 2 + c) ^ (r & 7)) << 3);

    f16x8 kpre[2], vpre[2];
    #pragma unroll
    for (int c = 0; c < 2; ++c) {
        kpre[c] = *(const f16x8*)(Kb + (size_t)r * HD_ + q4 * 16 + c * 8);
        vpre[c] = *(const f16x8*)(Vb + (size_t)r * S_ + q4 * 16 + c * 8);
    }

    for (int t = 0; t <= tq; ++t) {
        const int k0t = t * 64;
        __syncthreads();   // (A) prior iteration's tile reads done
        #pragma unroll
        for (int c = 0; c < 2; ++c) {
            *(f16x8*)&Ks[soff[c]]  = kpre[c];
            *(f16x8*)&Vth[soff[c]] = vpre[c];
        }
        __syncthreads();   // (B) tiles visible
        if (t < tq) {
            const int kn = k0t + 64;
            #pragma unroll
            for (int c = 0; c < 2; ++c) {
                kpre[c] = *(const f16x8*)(Kb + (size_t)(kn + r) * HD_ + q4 * 16 + c * 8);
                vpre[c] = *(const f16x8*)(Vb + (size_t)r * S_ + kn + q4 * 16 + c * 8);
            }
        }

        // ---- S^T = K Q^T (already in log2 domain; Q pre-scaled) ----
        f32x4 sf[4];
        #pragma unroll
        for (int f = 0; f < 4; ++f) sf[f] = (f32x4){0.f, 0.f, 0.f, 0.f};
        #pragma unroll
        for (int ch = 0; ch < 2; ++ch)
            #pragma unroll
            for (int f = 0; f < 4; ++f) {
                f16x8 ak = *(const f16x8*)
                    &Ks[(f * 16 + lr) * 64 + (((ch * 4 + quad) ^ (lr & 7)) << 3)];
                sf[f] = __builtin_amdgcn_mfma_f32_16x16x32_f16(ak, qf[ch], sf[f], 0, 0, 0);
            }

        // ---- zero-mask (diagonal tile only; reference zeroes pre-softmax) ----
        if (t == tq) {
            const int ig = q0 + w * 16 + lr;
            #pragma unroll
            for (int f = 0; f < 4; ++f)
                #pragma unroll
                for (int i = 0; i < 4; ++i) {
                    int jg = k0t + f * 16 + quad * 4 + i;
                    sf[f][i] = (jg <= ig) ? sf[f][i] : 0.f;
                }
        }

        // ---- softmax numerators, no max subtraction ----
        float ps = 0.f;
        #pragma unroll
        for (int f = 0; f < 4; ++f)
            #pragma unroll
            for (int i = 0; i < 4; ++i) {
                float p = exp2f(sf[f][i]);
                sf[f][i] = p;
                ps += p;
            }
        ps += __shfl_xor(ps, 16);
        ps += __shfl_xor(ps, 32);
        l_i += ps;

        // ---- P -> LDS as fp16 (one 8B write per frag; swizzled slot) ----
        #pragma unroll
        for (int f = 0; f < 4; ++f) {
            uint2 pw = make_uint2(pkrtz(sf[f][0], sf[f][1]),
                                  pkrtz(sf[f][2], sf[f][3]));
            *(uint2*)&Phi[(w * 16 + lr) * 64 +
                          (((f * 2 + (quad >> 1)) ^ (lr & 7)) << 3) +
                          (quad & 1) * 4] = pw;
        }

        // ---- O^T += V^T P^T  (in-wave LDS ordering; no barrier) ----
        #pragma unroll
        for (int ch = 0; ch < 2; ++ch) {
            f16x8 pb = *(const f16x8*)
                &Phi[(w * 16 + lr) * 64 + (((ch * 4 + quad) ^ (lr & 7)) << 3)];
            #pragma unroll
            for (int n = 0; n < 4; ++n) {
                f16x8 av = *(const f16x8*)
                    &Vth[(n * 16 + lr) * 64 + (((ch * 4 + quad) ^ (lr & 7)) << 3)];
                of[n] = __builtin_amdgcn_mfma_f32_16x16x32_f16(av, pb, of[n], 0, 0, 0);
            }
        }
    }

    // ---- masked-suffix contribution (weight 1) + normalize + store ----
    const int cnt = S_ - (q0 + 64);
    const float* suf = SUF + ((size_t)bh * (NT_ + 1) + (tq + 1)) * HD_;
    float inv = 1.0f / (l_i + (float)cnt);
    const int srow = q0 + w * 16 + lr;
    #pragma unroll
    for (int n = 0; n < 4; ++n) {
        float4 sv = *(const float4*)&suf[n * 16 + quad * 4];
        float4 ov;
        ov.x = (of[n][0] + sv.x) * inv;
        ov.y = (of[n][1] + sv.y) * inv;
        ov.z = (of[n][2] + sv.z) * inv;
        ov.w = (of[n][3] + sv.w) * inv;
        *(float4*)&OUT[((size_t)b * S_ + srow) * D_ + h * HD_ + n * 16 + quad * 4] = ov;
    }
}

// ---------------------------------------------------------------------------
extern "C" void kernel_launch(void* const* d_in, const int* in_sizes, int n_in,
                              void* d_out, int out_size, void* d_ws, size_t ws_size,
                              hipStream_t stream)
{
    (void)in_sizes; (void)n_in; (void)out_size; (void)ws_size;
    const float* q  = (const float*)d_in[0];
    const float* k  = (const float*)d_in[1];
    const float* v  = (const float*)d_in[2];
    const float* wq = (const float*)d_in[3];
    const float* wk = (const float*)d_in[4];
    const float* wv = (const float*)d_in[5];
    float* out = (float*)d_out;

    const size_t PROJ = (size_t)B_ * H_ * S_ * HD_;     // 4,194,304 elems
    const size_t WSZ  = (size_t)D_ * D_;                // 1,048,576 elems
    u16* QP = (u16*)d_ws;
    u16* KP = QP + PROJ;
    u16* VT = KP + PROJ;
    u16* Xq = VT + PROJ;
    u16* Xk = Xq + PROJ;
    u16* Xv = Xk + PROJ;
    u16* Wq = Xv + PROJ;
    u16* Wk = Wq + WSZ;
    u16* Wv = Wk + WSZ;
    float* TS  = (float*)(Wv + WSZ);
    float* SUF = TS + (size_t)B_ * H_ * NT_ * HD_;

    precast<<<dim3(PROJ / 1024, 6), 256, 0, stream>>>(
        wq, wk, wv, q, k, v, Wq, Wk, Wv, Xq, Xk, Xv);
    proj_all<<<dim3(3 * (D_ / 128) * ((B_ * S_) / 128)), 256, 0, stream>>>(
        Xq, Xk, Xv, Wq, Wk, Wv, QP, KP, VT, TS);
    vsuffix_kernel<<<B_ * H_, 64, 0, stream>>>(TS, SUF);
    attn_mfma<<<dim3(B_ * H_, NT_), 256, 0, stream>>>(QP, KP, VT, SUF, out);
}